// Round 6
// baseline (185.929 us; speedup 1.0000x reference)
//
#include <hip/hip_runtime.h>
#include <hip/hip_bf16.h>

// Problem dims (fixed by reference)
#define B_ROWS   8192
#define K_DIM    2048
#define OUT_COLS 4096
#define EPS      1e-5f

// GEMM tile: 256x256, BK=64, 8 waves (2M x 4N), mfma 16x16x32 (round-3 proven core).
// Persistent blocks: each block computes TWO C-tiles (same brow, bcol and bcol+8).
#define BM 256
#define BN 256
#define BK 64
#define NT (K_DIM / BK)   // 32 K-tiles per C-tile

using f32x4  = __attribute__((ext_vector_type(4))) float;
using bf16x8 = __attribute__((ext_vector_type(8))) short;   // 8 bf16 = 4 VGPRs

__device__ __forceinline__ unsigned short f2bf_rn(float f) {
    unsigned u = __builtin_bit_cast(unsigned, f);
    u += 0x7FFFu + ((u >> 16) & 1u);   // RNE (inputs finite)
    return (unsigned short)(u >> 16);
}

__global__ void cvt_all(const float* __restrict__ x, const float* __restrict__ w,
                        unsigned short* __restrict__ xb, unsigned short* __restrict__ wb) {
    const int n4x = (B_ROWS * K_DIM) / 4;
    const int n4w = (OUT_COLS * K_DIM) / 4;
    int stride = gridDim.x * blockDim.x;
    for (int i = blockIdx.x * blockDim.x + threadIdx.x; i < n4x + n4w; i += stride) {
        const float4* src; ushort4* dst; int j;
        if (i < n4x) { src = (const float4*)x; dst = (ushort4*)xb; j = i; }
        else         { src = (const float4*)w; dst = (ushort4*)wb; j = i - n4x; }
        float4 v = src[j];
        ushort4 r;
        r.x = f2bf_rn(v.x); r.y = f2bf_rn(v.y); r.z = f2bf_rn(v.z); r.w = f2bf_rn(v.w);
        dst[j] = r;
    }
}

__device__ __forceinline__ void gload16(const unsigned short* src, unsigned short* lds) {
    __builtin_amdgcn_global_load_lds((const __attribute__((address_space(1))) void*)src,
                                     (__attribute__((address_space(3))) void*)lds,
                                     16, 0, 0);
}

// 16-lane (DPP row) sum: after 4 row_ror steps every lane of the row holds the total
__device__ __forceinline__ float rowsum16(float v) {
    int x;
    x = __builtin_amdgcn_update_dpp(0, __builtin_bit_cast(int, v), 0x121, 0xF, 0xF, true);
    v += __builtin_bit_cast(float, x);
    x = __builtin_amdgcn_update_dpp(0, __builtin_bit_cast(int, v), 0x122, 0xF, 0xF, true);
    v += __builtin_bit_cast(float, x);
    x = __builtin_amdgcn_update_dpp(0, __builtin_bit_cast(int, v), 0x124, 0xF, 0xF, true);
    v += __builtin_bit_cast(float, x);
    x = __builtin_amdgcn_update_dpp(0, __builtin_bit_cast(int, v), 0x128, 0xF, 0xF, true);
    v += __builtin_bit_cast(float, x);
    return v;
}

// stage one half-tile (128 rows x 64 k): linear LDS dest, per-row XOR-permuted global src.
// A base is shared by both C-tiles (same brow); B base passed explicitly.
#define STA_(BUF, H, KT) do {                                                       \
    gload16(Ag + (H)*262144 + (KT)*64 + goff0, &As[BUF][(H)*8192 + lds0]);          \
    gload16(Ag + (H)*262144 + (KT)*64 + goff1, &As[BUF][(H)*8192 + lds1]);          \
  } while (0)
#define STB_(BASE, BUF, H, KT) do {                                                 \
    gload16((BASE) + (H)*262144 + (KT)*64 + goff0, &Bs[BUF][(H)*8192 + lds0]);      \
    gload16((BASE) + (H)*262144 + (KT)*64 + goff1, &Bs[BUF][(H)*8192 + lds1]);      \
  } while (0)

// read the 8 B-fragments of a tile (consumed starting NEXT phase)
#define RD_B(CURB) do {                                                             \
    _Pragma("unroll") for (int n = 0; n < 4; ++n) {                                 \
      const int ro = browb + n * 16 * BK;                                           \
      bb[n][0] = *(const bf16x8*)&(CURB)[ro + colsw0];                              \
      bb[n][1] = *(const bf16x8*)&(CURB)[ro + colsw1];                              \
    } } while (0)

// read one A-quadrant (2 m-frags x 2 k) into ping-pong slot (consumed NEXT phase)
#define RD_A(SLOT, CURA, Q) do {                                                    \
    _Pragma("unroll") for (int dm = 0; dm < 2; ++dm) {                              \
      const int ro = arow + (2*(Q)+dm) * 16 * BK;                                   \
      af[SLOT][dm][0] = *(const bf16x8*)&(CURA)[ro + colsw0];                       \
      af[SLOT][dm][1] = *(const bf16x8*)&(CURA)[ro + colsw1];                       \
    } } while (0)

#define MFMA16(SLOT, Q) do {                                                        \
    __builtin_amdgcn_s_setprio(1);                                                  \
    _Pragma("unroll") for (int kk = 0; kk < 2; ++kk)                                \
      _Pragma("unroll") for (int dm = 0; dm < 2; ++dm)                              \
        _Pragma("unroll") for (int n = 0; n < 4; ++n)                               \
          acc[2*(Q)+dm][n] = __builtin_amdgcn_mfma_f32_16x16x32_bf16(               \
              af[SLOT][dm][kk], bb[n][kk], acc[2*(Q)+dm][n], 0, 0, 0);              \
    __builtin_amdgcn_s_setprio(0);                                                  \
  } while (0)

#define VW4   asm volatile("s_waitcnt vmcnt(4)" ::: "memory")
#define VWALL asm volatile("s_waitcnt vmcnt(0)" ::: "memory")
#define BAR   __builtin_amdgcn_s_barrier()

// Phases P0..P6 of one 2-tile iteration. A-halves bunched at P0/P4, B-halves at
// P1/P5 => every half-tile is issued >=2 phases before its VW4 drain.
#define ITER7(K1, B2B, K2, B3B, K3)                                                 \
    RD_A(1, A0p, 1); STA_(1, 0, K1); STA_(1, 1, K1);           MFMA16(0, 0); BAR;   \
    RD_A(0, A0p, 2); STB_(B2B, 0, 0, K2); STB_(B2B, 0, 1, K2); MFMA16(1, 1); BAR;   \
    RD_A(1, A0p, 3);                                           MFMA16(0, 2); VW4; BAR; \
    RD_A(0, A1p, 0);                                           MFMA16(1, 3); RD_B(B1p); BAR; \
    RD_A(1, A1p, 1); STA_(0, 0, K2); STA_(0, 1, K2);           MFMA16(0, 0); BAR;   \
    RD_A(0, A1p, 2); STB_(B3B, 1, 0, K3); STB_(B3B, 1, 1, K3); MFMA16(1, 1); BAR;   \
    RD_A(1, A1p, 3);                                           MFMA16(0, 2); VW4; BAR;

#define ACC_INIT(OCB) do {                                                          \
    float bv[4];                                                                    \
    _Pragma("unroll") for (int n = 0; n < 4; ++n)                                   \
        bv[n] = bias[(OCB) + wcn * 64 + n * 16 + l16];                              \
    _Pragma("unroll") for (int m = 0; m < 8; ++m)                                   \
      _Pragma("unroll") for (int n = 0; n < 4; ++n)                                 \
        _Pragma("unroll") for (int j = 0; j < 4; ++j)                               \
            acc[m][n][j] = bv[n];                                                   \
  } while (0)

// GroupNorm epilogue for one C-tile (bias already inside acc). Uses dedicated redbuf.
#define EPILOGUE(OCB) do {                                                          \
    _Pragma("unroll") for (int m = 0; m < 8; ++m) {                                 \
      _Pragma("unroll") for (int j = 0; j < 4; ++j) {                               \
        float s = 0.f, s2 = 0.f;                                                    \
        _Pragma("unroll") for (int n = 0; n < 4; ++n) {                             \
            float v = acc[m][n][j]; s += v; s2 += v * v; }                          \
        s = rowsum16(s); s2 = rowsum16(s2);                                         \
        if (l16 == 0) {                                                             \
            int r = wr * 128 + m * 16 + lhi * 4 + j;                                \
            redbuf[r * 8 + wcn * 2 + 0] = s;                                        \
            redbuf[r * 8 + wcn * 2 + 1] = s2;                                       \
        } } }                                                                       \
    __syncthreads();                                                                \
    _Pragma("unroll") for (int m = 0; m < 8; ++m) {                                 \
      _Pragma("unroll") for (int j = 0; j < 4; ++j) {                               \
        const int r = wr * 128 + m * 16 + lhi * 4 + j;                              \
        const float4 q = *(const float4*)&redbuf[r * 8 + p2];                       \
        const float mean = (q.x + q.z) * (1.0f / 128.0f);                           \
        const float var  = (q.y + q.w) * (1.0f / 128.0f) - mean * mean;             \
        const float rstd = rsqrtf(var + EPS);                                       \
        float* orow = out + (size_t)(brow * 256 + r) * OUT_COLS + (OCB) + wcn * 64 + l16; \
        _Pragma("unroll") for (int n = 0; n < 4; ++n) {                             \
            float v = (acc[m][n][j] - mean) * rstd;                                 \
            v = fminf(fmaxf(v, -1.0f), 1.0f);                                       \
            orow[n * 16] = v; } } }                                                 \
    __syncthreads();                                                                \
  } while (0)

__global__ __launch_bounds__(512, 2) void gemm_gn(const unsigned short* __restrict__ A,
                                                  const unsigned short* __restrict__ Bw,
                                                  const float* __restrict__ bias,
                                                  float* __restrict__ out) {
    __shared__ __align__(16) unsigned short As[2][16384];   // 2 x 32 KB
    __shared__ __align__(16) unsigned short Bs[2][16384];   // 2 x 32 KB
    __shared__ __align__(16) float redbuf[256 * 8];         // 8 KB GN scratch

    const int tid  = threadIdx.x;
    const int lane = tid & 63;
    const int wave = tid >> 6;        // 0..7
    const int wr   = wave >> 2;       // 0..1 (M)
    const int wcn  = wave & 3;        // 0..3 (N)
    const int l16  = lane & 15;
    const int lhi  = lane >> 4;
    const int p2   = (wcn & 2) * 2;

    // T1 swizzle over 256 blocks (256 % 8 == 0): same-XCD neighbors share brow (A panel)
    const int bid  = blockIdx.x;
    const int swz  = (bid & 7) * 32 + (bid >> 3);
    const int brow = swz >> 3;        // 0..31
    const int bc0  = swz & 7;         // 0..7 ; this block owns bcol = bc0 and bc0+8

    // staging offsets: slot f -> row f>>3, chunk (f&7)^(row&7)  (round-3 proven)
    int goff0, goff1, lds0, lds1;
    {
        int f0 = tid;          int r0 = f0 >> 3;
        int f1 = 512 + tid;    int r1 = f1 >> 3;
        goff0 = r0 * K_DIM + (((f0 & 7) ^ (r0 & 7)) * 8);
        goff1 = r1 * K_DIM + (((f1 & 7) ^ (r1 & 7)) * 8);
        lds0  = f0 * 8;
        lds1  = f1 * 8;
    }
    const unsigned short* Ag  = A  + (size_t)brow * BM * K_DIM;           // shared by both tiles
    const unsigned short* Bg1 = Bw + (size_t)bc0 * BN * K_DIM;
    const unsigned short* Bg2 = Bw + (size_t)(bc0 + 8) * BN * K_DIM;
    const int ocb1 = bc0 * BN;
    const int ocb2 = (bc0 + 8) * BN;

    // swizzled fragment-read column offsets (ushort units)
    const int colsw0 = (0 * 32 + lhi * 8) ^ ((l16 & 7) << 3);
    const int colsw1 = (1 * 32 + lhi * 8) ^ ((l16 & 7) << 3);
    const int arow   = (wr * 128 + l16) * BK;
    const int browb  = (wcn * 64 + l16) * BK;

    const unsigned short* A0p = &As[0][0];
    const unsigned short* A1p = &As[1][0];
    const unsigned short* B0p = &Bs[0][0];
    const unsigned short* B1p = &Bs[1][0];

    f32x4  acc[8][4];
    bf16x8 af[2][2][2];
    bf16x8 bb[4][2];

    ACC_INIT(ocb1);

    // ---- prologue (tile 1): A(0), B(0), B(1); keep B(1)'s 4 loads in flight
    STA_(0, 0, 0); STA_(0, 1, 0);
    STB_(Bg1, 0, 0, 0); STB_(Bg1, 0, 1, 0);
    STB_(Bg1, 1, 0, 1); STB_(Bg1, 1, 1, 1);
    VW4;                       // A(0), B(0) resident
    BAR;
    RD_A(0, A0p, 0);
    RD_B(B0p);

    // ---- tile 1 main loop: tiles 0..29 ----
    #pragma unroll 1
    for (int tt = 0; tt < NT - 2; tt += 2) {
        ITER7(tt + 1, Bg1, tt + 2, Bg1, tt + 3)
        RD_A(0, A0p, 0); MFMA16(1, 3); RD_B(B0p); BAR;
    }
    // ---- hand-off iteration: tiles 30,31; stages tile-2's A(0),B2(0),B2(1) ----
    ITER7(NT - 1, Bg2, 0, Bg2, 1)
    MFMA16(1, 3); BAR;        // leaves B2(1)'s 4 loads in flight (loop invariant)

    EPILOGUE(ocb1);
    ACC_INIT(ocb2);

    // tile-2 pre-reads (A(0), B2(0) landed via hand-off VW4)
    RD_A(0, A0p, 0);
    RD_B(B0p);

    // ---- tile 2 main loop: tiles 0..29 ----
    #pragma unroll 1
    for (int tt = 0; tt < NT - 2; tt += 2) {
        ITER7(tt + 1, Bg2, tt + 2, Bg2, tt + 3)
        RD_A(0, A0p, 0); MFMA16(1, 3); RD_B(B0p); BAR;
    }
    // ---- terminal iteration: tiles 30,31; stage only A(31), drain everything ----
    RD_A(1, A0p, 1); STA_(1, 0, NT - 1); STA_(1, 1, NT - 1); MFMA16(0, 0); BAR;
    RD_A(0, A0p, 2);                                         MFMA16(1, 1); BAR;
    RD_A(1, A0p, 3);                                         MFMA16(0, 2); VWALL; BAR;
    RD_A(0, A1p, 0);                                         MFMA16(1, 3); RD_B(B1p); BAR;
    RD_A(1, A1p, 1);                                         MFMA16(0, 0); BAR;
    RD_A(0, A1p, 2);                                         MFMA16(1, 1); BAR;
    RD_A(1, A1p, 3);                                         MFMA16(0, 2); BAR;
    MFMA16(1, 3);

    EPILOGUE(ocb2);
}

extern "C" void kernel_launch(void* const* d_in, const int* in_sizes, int n_in,
                              void* d_out, int out_size, void* d_ws, size_t ws_size,
                              hipStream_t stream) {
    const float* x    = (const float*)d_in[0];   // [8192][2048]
    const float* w    = (const float*)d_in[1];   // [4096][2048]
    const float* bias = (const float*)d_in[2];   // [4096]
    float* out        = (float*)d_out;           // [8192][4096]

    unsigned short* xb = (unsigned short*)d_ws;
    unsigned short* wb = xb + (size_t)B_ROWS * K_DIM;

    cvt_all<<<3072, 256, 0, stream>>>(x, w, xb, wb);

    gemm_gn<<<256, 512, 0, stream>>>(xb, wb, bias, out);   // 1 block/CU, 2 C-tiles each
}

// Round 7
// 157.867 us; speedup vs baseline: 1.1778x; 1.1778x over previous
//
#include <hip/hip_runtime.h>
#include <hip/hip_bf16.h>

// Problem dims (fixed by reference)
#define B_ROWS   8192
#define K_DIM    2048
#define OUT_COLS 4096
#define EPS      1e-5f

// GEMM tile (round-3 proven core): 256x256, BK=64, 8 waves (2M x 4N), mfma 16x16x32,
// read-ahead 1-barrier phases, linear LDS dest + per-row XOR-permuted global source.
#define BM 256
#define BN 256
#define BK 64
#define NT (K_DIM / BK)   // 32 K-tiles

using f32x4  = __attribute__((ext_vector_type(4))) float;
using bf16x8 = __attribute__((ext_vector_type(8))) short;   // 8 bf16 = 4 VGPRs

__device__ __forceinline__ unsigned short f2bf_rn(float f) {
    unsigned u = __builtin_bit_cast(unsigned, f);
    u += 0x7FFFu + ((u >> 16) & 1u);   // RNE (inputs finite)
    return (unsigned short)(u >> 16);
}

__global__ void cvt_all(const float* __restrict__ x, const float* __restrict__ w,
                        unsigned short* __restrict__ xb, unsigned short* __restrict__ wb) {
    const int n4x = (B_ROWS * K_DIM) / 4;
    const int n4w = (OUT_COLS * K_DIM) / 4;
    int stride = gridDim.x * blockDim.x;
    for (int i = blockIdx.x * blockDim.x + threadIdx.x; i < n4x + n4w; i += stride) {
        const float4* src; ushort4* dst; int j;
        if (i < n4x) { src = (const float4*)x; dst = (ushort4*)xb; j = i; }
        else         { src = (const float4*)w; dst = (ushort4*)wb; j = i - n4x; }
        float4 v = src[j];
        ushort4 r;
        r.x = f2bf_rn(v.x); r.y = f2bf_rn(v.y); r.z = f2bf_rn(v.z); r.w = f2bf_rn(v.w);
        dst[j] = r;
    }
}

__device__ __forceinline__ void gload16(const unsigned short* src, unsigned short* lds) {
    __builtin_amdgcn_global_load_lds((const __attribute__((address_space(1))) void*)src,
                                     (__attribute__((address_space(3))) void*)lds,
                                     16, 0, 0);
}

// 16-lane row sum via DPP row_ror (pure VALU, no LDS pipe): all lanes get the total
__device__ __forceinline__ float rowsum16(float v) {
    int x;
    x = __builtin_amdgcn_update_dpp(0, __builtin_bit_cast(int, v), 0x121, 0xF, 0xF, true);
    v += __builtin_bit_cast(float, x);
    x = __builtin_amdgcn_update_dpp(0, __builtin_bit_cast(int, v), 0x122, 0xF, 0xF, true);
    v += __builtin_bit_cast(float, x);
    x = __builtin_amdgcn_update_dpp(0, __builtin_bit_cast(int, v), 0x124, 0xF, 0xF, true);
    v += __builtin_bit_cast(float, x);
    x = __builtin_amdgcn_update_dpp(0, __builtin_bit_cast(int, v), 0x128, 0xF, 0xF, true);
    v += __builtin_bit_cast(float, x);
    return v;
}

// stage one half-tile (128 rows x 64 k): linear LDS dest, per-row XOR-permuted global src
#define STA(BUF, H, KT) do {                                                        \
    gload16(Ag + (H)*262144 + (KT)*64 + goff0, &As[BUF][(H)*8192 + lds0]);          \
    gload16(Ag + (H)*262144 + (KT)*64 + goff1, &As[BUF][(H)*8192 + lds1]);          \
  } while (0)
#define STB(BUF, H, KT) do {                                                        \
    gload16(Bg + (H)*262144 + (KT)*64 + goff0, &Bs[BUF][(H)*8192 + lds0]);          \
    gload16(Bg + (H)*262144 + (KT)*64 + goff1, &Bs[BUF][(H)*8192 + lds1]);          \
  } while (0)

// read the 8 B-fragments of a tile (consumed starting NEXT phase)
#define RD_B(CURB) do {                                                             \
    _Pragma("unroll") for (int n = 0; n < 4; ++n) {                                 \
      const int ro = browb + n * 16 * BK;                                           \
      bb[n][0] = *(const bf16x8*)&(CURB)[ro + colsw0];                              \
      bb[n][1] = *(const bf16x8*)&(CURB)[ro + colsw1];                              \
    } } while (0)

// read one A-quadrant (2 m-frags x 2 k) into ping-pong slot (consumed NEXT phase)
#define RD_A(SLOT, CURA, Q) do {                                                    \
    _Pragma("unroll") for (int dm = 0; dm < 2; ++dm) {                              \
      const int ro = arow + (2*(Q)+dm) * 16 * BK;                                   \
      af[SLOT][dm][0] = *(const bf16x8*)&(CURA)[ro + colsw0];                       \
      af[SLOT][dm][1] = *(const bf16x8*)&(CURA)[ro + colsw1];                       \
    } } while (0)

#define MFMA16(SLOT, Q) do {                                                        \
    __builtin_amdgcn_s_setprio(1);                                                  \
    _Pragma("unroll") for (int kk = 0; kk < 2; ++kk)                                \
      _Pragma("unroll") for (int dm = 0; dm < 2; ++dm)                              \
        _Pragma("unroll") for (int n = 0; n < 4; ++n)                               \
          acc[2*(Q)+dm][n] = __builtin_amdgcn_mfma_f32_16x16x32_bf16(               \
              af[SLOT][dm][kk], bb[n][kk], acc[2*(Q)+dm][n], 0, 0, 0);              \
    __builtin_amdgcn_s_setprio(0);                                                  \
  } while (0)

#define VW4  asm volatile("s_waitcnt vmcnt(4)" ::: "memory")
#define BAR  __builtin_amdgcn_s_barrier()

__global__ __launch_bounds__(512, 2) void gemm_gn(const unsigned short* __restrict__ A,
                                                  const unsigned short* __restrict__ Bw,
                                                  const float* __restrict__ bias,
                                                  float* __restrict__ out) {
    __shared__ __align__(16) unsigned short As[2][16384];   // 2 x 32 KB
    __shared__ __align__(16) unsigned short Bs[2][16384];   // 2 x 32 KB
    __shared__ __align__(16) float redbuf[256 * 8];         // 8 KB GN scratch (dedicated)

    const int tid  = threadIdx.x;
    const int lane = tid & 63;
    const int wave = tid >> 6;        // 0..7
    const int wr   = wave >> 2;       // 0..1 (M)
    const int wcn  = wave & 3;        // 0..3 (N)
    const int l16  = lane & 15;
    const int lhi  = lane >> 4;

    // T1: XCD-aware bijective swizzle (512 % 8 == 0)
    const int bid  = blockIdx.x;
    const int swz  = (bid & 7) * (gridDim.x >> 3) + (bid >> 3);
    const int brow = swz >> 4;        // 0..31
    const int bcol = swz & 15;        // 0..15

    // staging offsets: slot f -> row f>>3, chunk (f&7)^(row&7)
    int goff0, goff1, lds0, lds1;
    {
        int f0 = tid;          int r0 = f0 >> 3;
        int f1 = 512 + tid;    int r1 = f1 >> 3;
        goff0 = r0 * K_DIM + (((f0 & 7) ^ (r0 & 7)) * 8);
        goff1 = r1 * K_DIM + (((f1 & 7) ^ (r1 & 7)) * 8);
        lds0  = f0 * 8;
        lds1  = f1 * 8;
    }
    const unsigned short* Ag = A  + (size_t)brow * BM * K_DIM;
    const unsigned short* Bg = Bw + (size_t)bcol * BN * K_DIM;

    // swizzled fragment-read column offsets (ushort units); row&7 == l16&7
    const int colsw0 = (0 * 32 + lhi * 8) ^ ((l16 & 7) << 3);
    const int colsw1 = (1 * 32 + lhi * 8) ^ ((l16 & 7) << 3);
    const int arow   = (wr * 128 + l16) * BK;
    const int browb  = (wcn * 64 + l16) * BK;

    const unsigned short* A0p = &As[0][0];
    const unsigned short* A1p = &As[1][0];
    const unsigned short* B0p = &Bs[0][0];
    const unsigned short* B1p = &Bs[1][0];

    // bias folded into accumulator init: every C-reg of acc[m][n] belongs to
    // column (bcol*BN + wcn*64 + n*16 + l16), so init all 4 regs with its bias.
    f32x4  acc[8][4];
    {
        float bv[4];
        #pragma unroll
        for (int n = 0; n < 4; ++n)
            bv[n] = bias[bcol * BN + wcn * 64 + n * 16 + l16];
        #pragma unroll
        for (int m = 0; m < 8; ++m)
            #pragma unroll
            for (int n = 0; n < 4; ++n)
                #pragma unroll
                for (int j = 0; j < 4; ++j)
                    acc[m][n][j] = bv[n];
    }

    bf16x8 af[2][2][2];
    bf16x8 bb[4][2];

    // ---- prologue: A(0)->As0, B(0)->Bs0, B(1)->Bs1; leave B(1)'s 4 in flight
    STA(0, 0, 0); STA(0, 1, 0);
    STB(0, 0, 0); STB(0, 1, 0);
    STB(1, 0, 1); STB(1, 1, 1);
    VW4;                       // A(0), B(0) landed
    BAR;
    RD_A(0, A0p, 0);           // in flight for ph0
    RD_B(B0p);

    #pragma unroll 1
    for (int tt = 0; tt < NT; tt += 2) {
        const int k1 = (tt + 1) & (NT - 1);
        const int k2 = (tt + 2) & (NT - 1);
        const int k3 = (tt + 3) & (NT - 1);
        // ---- tile tt (buf0) ----
        RD_A(1, A0p, 1); STA(1, 0, k1);               MFMA16(0, 0);       BAR;
        RD_A(0, A0p, 2); STA(1, 1, k1); STB(0, 0, k2); MFMA16(1, 1);      BAR;
        RD_A(1, A0p, 3); STB(0, 1, k2);               MFMA16(0, 2); VW4;  BAR;
        RD_A(0, A1p, 0);                              MFMA16(1, 3); RD_B(B1p); BAR;
        // ---- tile tt+1 (buf1) ----
        RD_A(1, A1p, 1); STA(0, 0, k2);               MFMA16(0, 0);       BAR;
        RD_A(0, A1p, 2); STA(0, 1, k2); STB(1, 0, k3); MFMA16(1, 1);      BAR;
        RD_A(1, A1p, 3); STB(1, 1, k3);               MFMA16(0, 2); VW4;  BAR;
        RD_A(0, A0p, 0);                              MFMA16(1, 3); RD_B(B0p); BAR;
    }

    // ---- epilogue: GroupNorm over 128-col groups (block-local), clip, store ----
    // pass 1: per-row (s, s2) over this wave's 64 cols; DPP reduce; redbuf is
    // dedicated so no drain needed before starting.
    // C/D layout (16x16): col = lane&15, row = (lane>>4)*4 + j
    #pragma unroll
    for (int m = 0; m < 8; ++m) {
        #pragma unroll
        for (int j = 0; j < 4; ++j) {
            float s = 0.f, s2 = 0.f;
            #pragma unroll
            for (int n = 0; n < 4; ++n) {
                float v = acc[m][n][j];
                s += v; s2 += v * v;
            }
            s  = rowsum16(s);
            s2 = rowsum16(s2);
            if (l16 == 0) {
                int r = wr * 128 + m * 16 + lhi * 4 + j;
                redbuf[r * 8 + wcn * 2 + 0] = s;
                redbuf[r * 8 + wcn * 2 + 1] = s2;
            }
        }
    }
    // drain in-flight dummy stages (wrapped kt) before kernel end; free here
    asm volatile("s_waitcnt vmcnt(0)" ::: "memory");
    __syncthreads();

    // pass 2: combine wave pair per 128-col group (float4 broadcast), normalize, clip, store
    const int p2 = (wcn & 2) * 2;
    #pragma unroll
    for (int m = 0; m < 8; ++m) {
        #pragma unroll
        for (int j = 0; j < 4; ++j) {
            const int r = wr * 128 + m * 16 + lhi * 4 + j;
            const float4 q = *(const float4*)&redbuf[r * 8 + p2];
            const float mean = (q.x + q.z) * (1.0f / 128.0f);
            const float var  = (q.y + q.w) * (1.0f / 128.0f) - mean * mean;
            const float rstd = rsqrtf(var + EPS);
            float* orow = out + (size_t)(brow * BM + r) * OUT_COLS + bcol * BN + wcn * 64 + l16;
            #pragma unroll
            for (int n = 0; n < 4; ++n) {
                float v = (acc[m][n][j] - mean) * rstd;
                v = fminf(fmaxf(v, -1.0f), 1.0f);
                orow[n * 16] = v;
            }
        }
    }
}

extern "C" void kernel_launch(void* const* d_in, const int* in_sizes, int n_in,
                              void* d_out, int out_size, void* d_ws, size_t ws_size,
                              hipStream_t stream) {
    const float* x    = (const float*)d_in[0];   // [8192][2048]
    const float* w    = (const float*)d_in[1];   // [4096][2048]
    const float* bias = (const float*)d_in[2];   // [4096]
    float* out        = (float*)d_out;           // [8192][4096]

    unsigned short* xb = (unsigned short*)d_ws;
    unsigned short* wb = xb + (size_t)B_ROWS * K_DIM;

    cvt_all<<<3072, 256, 0, stream>>>(x, w, xb, wb);

    dim3 grid((B_ROWS / BM) * (OUT_COLS / BN));   // 32 * 16 = 512
    gemm_gn<<<grid, 512, 0, stream>>>(xb, wb, bias, out);
}